// Round 6
// baseline (133.924 us; speedup 1.0000x reference)
//
#include <hip/hip_runtime.h>
#include <stdint.h>

#define NUM_H 16
#define HD    64
#define CDIM  1024
#define NSEQ  2048
#define NBATCH 2
#define LOG2E 1.4426950408889634f

typedef __attribute__((ext_vector_type(8))) short short8;
typedef __attribute__((ext_vector_type(4))) float f32x4;
typedef __attribute__((ext_vector_type(16))) float f32x16;
typedef __attribute__((ext_vector_type(4))) unsigned short ushort4v;
typedef __attribute__((ext_vector_type(4))) float float4v;
typedef __attribute__((ext_vector_type(2))) unsigned int u32x2;

__device__ __forceinline__ unsigned short f2bf(float f) {
    unsigned int u = __builtin_bit_cast(unsigned int, f);
    unsigned int r = u + 0x7fffu + ((u >> 16) & 1u);
    return (unsigned short)(r >> 16);
}

__device__ __forceinline__ unsigned int cvtpk(float a, float b) {
    unsigned int r;
    asm("v_cvt_pk_bf16_f32 %0, %1, %2" : "=v"(r) : "v"(a), "v"(b));
    return r;
}

__device__ __forceinline__ void plswap(unsigned int &a, unsigned int &b) {
    asm("v_permlane32_swap_b32 %0, %1" : "+v"(a), "+v"(b));
}

// global -> LDS async copy, 16B per lane. LDS dest is wave-uniform base + lane*16.
__device__ __forceinline__ void gload_lds16(const void* g, const void* l) {
    __builtin_amdgcn_global_load_lds(
        (const __attribute__((address_space(1))) unsigned int*)(unsigned long long)(uintptr_t)g,
        (__attribute__((address_space(3))) unsigned int*)(unsigned int)(uintptr_t)l,
        16, 0, 0);
}

__global__ void cvt_bf16_kernel(const float* __restrict__ in,
                                unsigned short* __restrict__ out, int n4) {
    int i = blockIdx.x * blockDim.x + threadIdx.x;
    if (i < n4) {
        float4v v = *(const float4v*)(in + (size_t)i * 4);
        ushort4v o;
        o[0] = f2bf(v[0]); o[1] = f2bf(v[1]); o[2] = f2bf(v[2]); o[3] = f2bf(v[3]);
        *(ushort4v*)(out + (size_t)i * 4) = o;
    }
}

// ---------------- GEMM1: qkv = x @ qkv_w^T + b : 256x256 8-phase (T3+T4) ----------------
// 8 waves (2M x 4N), BK=64, 128KB LDS dbuf, raw s_barrier + counted vmcnt(8).
// Staging ledger (tile t+2 goes into the buffer tile t is reading):
//   B-half0 last ds_read at phase 0  -> staged at phase 1
//   B-half1 last ds_read at phase 1  -> staged at phase 2
//   A-half0/A-half1 last ds_read at phase 2 -> both staged at phase 3
// One vmcnt(8) per iter: waits tile t+1's 8 loads (oldest), keeps t+2's 8 in flight.
// K output is PRE-SCALED by 0.125*(1+0.2*pw[h]*ps[b])*LOG2E.
__global__ __launch_bounds__(512, 2) void gemm_qkv(
    const unsigned short* __restrict__ A,   // x_bf  [4096][1024]
    const unsigned short* __restrict__ Bw,  // w1_bf [3072][1024]
    const float* __restrict__ bias,         // qkv_b [3072]
    const float* __restrict__ ps,           // phase_signal [2]
    const float* __restrict__ pw,           // phase_weight [16]
    unsigned short* __restrict__ qb,        // [B,H,N,D]
    unsigned short* __restrict__ kb,        // [B,H,N,D]  (pre-scaled)
    unsigned short* __restrict__ vtb)       // [B,H,D,N]  (transposed V)
{
    __shared__ unsigned short lds[2][2][2][128][64];  // [buf][A/B][half][row][col] = 128 KB

    const int tid = threadIdx.x;
    const int wid = tid >> 6;            // 0..7
    const int lane = tid & 63;
    const int l15 = lane & 15, l4 = lane >> 4;
    const int wave_m = wid >> 2, wave_n = wid & 3;

    const int bm = blockIdx.x;           // 16
    const int bn = blockIdx.y;           // 12

    f32x4 acc[8][4];
    const f32x4 zero4 = {0.f, 0.f, 0.f, 0.f};
#pragma unroll
    for (int m = 0; m < 8; ++m)
#pragma unroll
        for (int n = 0; n < 4; ++n) acc[m][n] = zero4;

    // staging lane geometry: 8 rows x 8 slots per load instr, inverse-swizzled source
    const int jr = lane >> 3;
    const int jc = ((lane & 7) ^ jr) << 4;
    const char* aB = (const char*)A  + (size_t)(bm * 256) * 2048;
    const char* bB = (const char*)Bw + (size_t)(bn * 256) * 2048;

    // half-tile stage: which: 0=A-half0, 1=A-half1, 2=B-half0, 3=B-half1
    auto stageH = [&](int t, int which) {
        const int buf = t & 1;
        const int op = which >> 1, hf = which & 1;
        const char* src = (op == 0) ? aB : bB;
        const int rowb = hf * 128 + wid * 16;
        const size_t k0b = (size_t)t * 128;
        char* dst = (char*)&lds[buf][op][hf][wid * 16][0];
#pragma unroll
        for (int i = 0; i < 2; ++i)
            gload_lds16(src + (size_t)(rowb + i * 8 + jr) * 2048 + k0b + jc,
                        dst + i * 1024);
    };

    const int swz = (l15 & 7) << 4;
    auto rdA = [&](int buf, int mq, int mp, int kk) -> short8 {
        return *(const short8*)((const char*)&lds[buf][0][wave_m][mq * 64 + mp * 16 + l15][0]
                                + ((kk * 64 + l4 * 16) ^ swz));
    };
    auto rdB = [&](int buf, int nq, int np, int kk) -> short8 {
        const int br = wave_n * 64 + nq * 32 + np * 16 + l15;
        return *(const short8*)((const char*)&lds[buf][1][br >> 7][br & 127][0]
                                + ((kk * 64 + l4 * 16) ^ swz));
    };

    // prologue: tile 0 (8 loads, oldest) + tile 1 (8 loads); vmcnt(8) = tile 0 landed
    stageH(0, 0); stageH(0, 1); stageH(0, 2); stageH(0, 3);
    stageH(1, 2); stageH(1, 3); stageH(1, 0); stageH(1, 1);
    asm volatile("s_waitcnt vmcnt(8)" ::: "memory");
    __builtin_amdgcn_s_barrier();

    for (int t = 0; t < 16; ++t) {
        const int buf = t & 1;
        short8 af[4][2], bf[2][2][2];

        // ---- phase 0: quadrant (mq=0, nq=0); no stage
#pragma unroll
        for (int mp = 0; mp < 4; ++mp) {
            af[mp][0] = rdA(buf, 0, mp, 0); af[mp][1] = rdA(buf, 0, mp, 1);
        }
#pragma unroll
        for (int np = 0; np < 2; ++np) {
            bf[0][np][0] = rdB(buf, 0, np, 0); bf[0][np][1] = rdB(buf, 0, np, 1);
        }
        __builtin_amdgcn_s_barrier();
        __builtin_amdgcn_s_setprio(1);
#pragma unroll
        for (int mp = 0; mp < 4; ++mp)
#pragma unroll
            for (int np = 0; np < 2; ++np)
#pragma unroll
                for (int kk = 0; kk < 2; ++kk)
                    acc[mp][np] = __builtin_amdgcn_mfma_f32_16x16x32_bf16(
                        af[mp][kk], bf[0][np][kk], acc[mp][np], 0, 0, 0);
        __builtin_amdgcn_s_setprio(0);
        __builtin_amdgcn_s_barrier();

        // ---- phase 1: (0,1); stage H(t+2, B-half0) (B0 reads finished at phase 0)
#pragma unroll
        for (int np = 0; np < 2; ++np) {
            bf[1][np][0] = rdB(buf, 1, np, 0); bf[1][np][1] = rdB(buf, 1, np, 1);
        }
        if (t < 14) stageH(t + 2, 2);
        __builtin_amdgcn_s_barrier();
        __builtin_amdgcn_s_setprio(1);
#pragma unroll
        for (int mp = 0; mp < 4; ++mp)
#pragma unroll
            for (int np = 0; np < 2; ++np)
#pragma unroll
                for (int kk = 0; kk < 2; ++kk)
                    acc[mp][2 + np] = __builtin_amdgcn_mfma_f32_16x16x32_bf16(
                        af[mp][kk], bf[1][np][kk], acc[mp][2 + np], 0, 0, 0);
        __builtin_amdgcn_s_setprio(0);
        __builtin_amdgcn_s_barrier();

        // ---- phase 2: (1,0); stage H(t+2, B-half1) (B1 reads finished at phase 1)
#pragma unroll
        for (int mp = 0; mp < 4; ++mp) {
            af[mp][0] = rdA(buf, 1, mp, 0); af[mp][1] = rdA(buf, 1, mp, 1);
        }
        if (t < 14) stageH(t + 2, 3);
        __builtin_amdgcn_s_barrier();
        __builtin_amdgcn_s_setprio(1);
#pragma unroll
        for (int mp = 0; mp < 4; ++mp)
#pragma unroll
            for (int np = 0; np < 2; ++np)
#pragma unroll
                for (int kk = 0; kk < 2; ++kk)
                    acc[4 + mp][np] = __builtin_amdgcn_mfma_f32_16x16x32_bf16(
                        af[mp][kk], bf[0][np][kk], acc[4 + mp][np], 0, 0, 0);
        __builtin_amdgcn_s_setprio(0);
        __builtin_amdgcn_s_barrier();

        // ---- phase 3: (1,1); stage H(t+2, A-half0+A-half1) (A reads finished at phase 2);
        //      counted vmcnt(8) at tile boundary = tile t+1 landed, t+2 in flight
        if (t < 14) { stageH(t + 2, 0); stageH(t + 2, 1); }
        __builtin_amdgcn_s_barrier();
        __builtin_amdgcn_s_setprio(1);
#pragma unroll
        for (int mp = 0; mp < 4; ++mp)
#pragma unroll
            for (int np = 0; np < 2; ++np)
#pragma unroll
                for (int kk = 0; kk < 2; ++kk)
                    acc[4 + mp][2 + np] = __builtin_amdgcn_mfma_f32_16x16x32_bf16(
                        af[mp][kk], bf[1][np][kk], acc[4 + mp][2 + np], 0, 0, 0);
        __builtin_amdgcn_s_setprio(0);
        if (t < 14)       { asm volatile("s_waitcnt vmcnt(8)" ::: "memory"); }
        else if (t == 14) { asm volatile("s_waitcnt vmcnt(0)" ::: "memory"); }
        __builtin_amdgcn_s_barrier();
    }

    // epilogue: scatter q/k/vt (k pre-scaled)
    const int row_base = bm * 256 + wave_m * 128;
    const int col_base = bn * 256 + wave_n * 64;
    const float ps0 = ps[0], ps1 = ps[1];
#pragma unroll
    for (int n = 0; n < 4; ++n) {
        const int col3 = col_base + n * 16 + l15;
        const float bv = bias[col3];
        const int t3 = col3 >> 10;
        const int hh = (col3 >> 6) & 15;
        const int dd = col3 & 63;
        float kf0 = 1.f, kf1 = 1.f;
        if (t3 == 1) {
            const float base = 0.125f * LOG2E;
            const float pwh = pw[hh];
            kf0 = base * (1.f + 0.2f * pwh * ps0);
            kf1 = base * (1.f + 0.2f * pwh * ps1);
        }
#pragma unroll
        for (int m = 0; m < 8; ++m) {
#pragma unroll
            for (int r = 0; r < 4; ++r) {
                const int row = row_base + m * 16 + l4 * 4 + r;
                const int bb = row >> 11, nn = row & 2047;
                const size_t bh = (size_t)(bb * 16 + hh);
                if (t3 == 0) {
                    qb[(bh * 2048 + nn) * 64 + dd] = f2bf(acc[m][n][r] + bv);
                } else if (t3 == 1) {
                    const float kf = (bb == 0) ? kf0 : kf1;
                    kb[(bh * 2048 + nn) * 64 + dd] = f2bf((acc[m][n][r] + bv) * kf);
                } else {
                    vtb[(bh * 64 + dd) * 2048 + nn] = f2bf(acc[m][n][r] + bv);
                }
            }
        }
    }
}

// ---------------- GEMM2: out = attn @ proj_w^T + b (fp32 out) ----------------
// 128^2 2-phase dbuf; NATURAL block order (XCD = bm%8 partitions A cleanly).
__global__ __launch_bounds__(256, 2) void gemm_proj(
    const unsigned short* __restrict__ A,   // attn_bf [4096][1024]
    const unsigned short* __restrict__ Bw,  // wp_bf   [1024][1024]
    const float* __restrict__ bias,         // proj_b  [1024]
    float* __restrict__ out)                // [4096][1024] fp32
{
    __shared__ unsigned short As[2][128 * 64];
    __shared__ unsigned short Bs[2][128 * 64];
    const int tid = threadIdx.x;
    const int wid = tid >> 6;
    const int lane = tid & 63;
    const int l15 = lane & 15, l4 = lane >> 4;
    const int bm = blockIdx.x, bn = blockIdx.y;
    const int wr = wid >> 1, wc = wid & 1;

    f32x4 acc[4][4];
    const f32x4 zero4 = {0.f, 0.f, 0.f, 0.f};
#pragma unroll
    for (int m = 0; m < 4; ++m)
#pragma unroll
        for (int n = 0; n < 4; ++n) acc[m][n] = zero4;

    const int jr = lane >> 3;
    const int jc = ((lane & 7) ^ jr) << 4;
    const char* aB = (const char*)A  + (size_t)(bm * 128) * 2048;
    const char* bB = (const char*)Bw + (size_t)(bn * 128) * 2048;

    auto stage = [&](int buf, int k0) {
#pragma unroll
        for (int i = 0; i < 4; ++i) {
            const int rowb = wid * 32 + i * 8;
            gload_lds16(aB + (size_t)(rowb + jr) * 2048 + k0 * 2 + jc,
                        (const char*)&As[buf][0] + rowb * 128);
            gload_lds16(bB + (size_t)(rowb + jr) * 2048 + k0 * 2 + jc,
                        (const char*)&Bs[buf][0] + rowb * 128);
        }
    };

    const int swz = (l15 & 7) << 4;

    stage(0, 0);
    for (int it = 0; it < 16; ++it) {
        const int buf = it & 1;
        __syncthreads();
        if (it < 15) stage(buf ^ 1, (it + 1) * 64);
#pragma unroll
        for (int kk = 0; kk < 2; ++kk) {
            short8 a[4], b[4];
#pragma unroll
            for (int m = 0; m < 4; ++m)
                a[m] = *(const short8*)((const char*)&As[buf][0] +
                        (wr * 64 + m * 16 + l15) * 128 + ((kk * 64 + l4 * 16) ^ swz));
#pragma unroll
            for (int n = 0; n < 4; ++n)
                b[n] = *(const short8*)((const char*)&Bs[buf][0] +
                        (wc * 64 + n * 16 + l15) * 128 + ((kk * 64 + l4 * 16) ^ swz));
            __builtin_amdgcn_s_setprio(1);
#pragma unroll
            for (int m = 0; m < 4; ++m)
#pragma unroll
                for (int n = 0; n < 4; ++n)
                    acc[m][n] = __builtin_amdgcn_mfma_f32_16x16x32_bf16(a[m], b[n], acc[m][n], 0, 0, 0);
            __builtin_amdgcn_s_setprio(0);
        }
    }

    const int row_base = bm * 128 + wr * 64;
    const int col_base = bn * 128 + wc * 64;
#pragma unroll
    for (int n = 0; n < 4; ++n) {
        const int col = col_base + n * 16 + l15;
        const float bv = bias[col];
#pragma unroll
        for (int m = 0; m < 4; ++m) {
#pragma unroll
            for (int r = 0; r < 4; ++r) {
                const int row = row_base + m * 16 + l4 * 4 + r;
                out[(size_t)row * 1024 + col] = acc[m][n][r] + bv;
            }
        }
    }
}

// ---------------- Flash attention, swapped-QK^T, STATIC-SHIFT softmax ----------------
__global__ __launch_bounds__(256, 2) void attn_kernel(
    const unsigned short* __restrict__ qb,   // [B,H,N,D]
    const unsigned short* __restrict__ kb,   // [B,H,N,D] pre-scaled
    const unsigned short* __restrict__ vtb,  // [B,H,D,N]
    unsigned short* __restrict__ aout)       // [B*N][C] bf16
{
    __shared__ unsigned short KVs[2][2][64 * 64];   // [buf][K/V][row*64 + col] = 32 KB

    const int tid = threadIdx.x;
    const int w = tid >> 6;
    const int l = tid & 63;
    const int l31 = l & 31;
    const int hi = l >> 5;

    // T1: bijective XCD remap (nwg=512, 64/XCD): 16 q-tiles of a bh stay on one XCD
    const int bid = blockIdx.y * 16 + blockIdx.x;
    const int wg = (bid & 7) * 64 + (bid >> 3);
    const int bh = wg >> 4;
    const int b = bh >> 4, h = bh & 15;
    const int q0 = (wg & 15) * 128 + w * 32;

    const char* qg = (const char*)(qb + (size_t)bh * 2048 * 64);
    const char* kg = (const char*)(kb + (size_t)bh * 2048 * 64);
    const char* vg = (const char*)(vtb + (size_t)bh * 64 * 2048);

    short8 qf[4];
#pragma unroll
    for (int t = 0; t < 4; ++t)
        qf[t] = *(const short8*)(qg + (size_t)(q0 + l31) * 128 + t * 32 + hi * 16);

    f32x16 oacc[2];
#pragma unroll
    for (int dt = 0; dt < 2; ++dt)
#pragma unroll
        for (int r = 0; r < 16; ++r) oacc[dt][r] = 0.f;
    float lr = 0.f;

    const int jr = l >> 3;
    const int jc = ((l & 7) ^ jr) << 4;
    auto stage = [&](int buf, int kv0) {
#pragma unroll
        for (int i = 0; i < 2; ++i) {
            const int row = w * 16 + i * 8;
            gload_lds16(kg + (size_t)(kv0 + row + jr) * 128 + jc,
                        (const char*)&KVs[buf][0][0] + row * 128);
            gload_lds16(vg + (size_t)(row + jr) * 4096 + (size_t)kv0 * 2 + jc,
                        (const char*)&KVs[buf][1][0] + row * 128);
        }
    };

    stage(0, 0);
    __syncthreads();

    const int swz = (l31 & 7) << 4;

    for (int it = 0; it < 32; ++it) {
        const int buf = it & 1;
        if (it < 31) stage(buf ^ 1, (it + 1) * 64);

        const char* Kb = (const char*)&KVs[buf][0][0];
        const char* Vb = (const char*)&KVs[buf][1][0];

        f32x16 sa[2];
        __builtin_amdgcn_s_setprio(1);
#pragma unroll
        for (int s = 0; s < 2; ++s) {
#pragma unroll
            for (int r = 0; r < 16; ++r) sa[s][r] = 0.f;
#pragma unroll
            for (int t = 0; t < 4; ++t) {
                const short8 kf = *(const short8*)(Kb + (s * 32 + l31) * 128 +
                                                   ((t * 32 + hi * 16) ^ swz));
                sa[s] = __builtin_amdgcn_mfma_f32_32x32x16_bf16(kf, qf[t], sa[s], 0, 0, 0);
            }
        }
        __builtin_amdgcn_s_setprio(0);

        // static-shift softmax: P = 2^(s-20); uniform scale cancels in O/lr
#pragma unroll
        for (int s = 0; s < 2; ++s)
#pragma unroll
            for (int r = 0; r < 16; ++r)
                sa[s][r] = __builtin_amdgcn_exp2f(sa[s][r] - 20.0f);

        float ts[16];
#pragma unroll
        for (int r = 0; r < 16; ++r) ts[r] = sa[0][r] + sa[1][r];
#pragma unroll
        for (int d = 8; d >= 1; d >>= 1)
#pragma unroll
            for (int r = 0; r < 8; ++r)
                if (r < d) ts[r] += ts[r + d];
        lr += ts[0] + __shfl_xor(ts[0], 32);

#pragma unroll
        for (int s = 0; s < 2; ++s) {
            unsigned int wv[8];
#pragma unroll
            for (int g = 0; g < 8; ++g)
                wv[g] = cvtpk(sa[s][g * 2], sa[s][g * 2 + 1]);
            plswap(wv[0], wv[2]); plswap(wv[1], wv[3]);
            plswap(wv[4], wv[6]); plswap(wv[5], wv[7]);
            union { unsigned int u[4]; short8 s8; } f0, f1;
            f0.u[0] = wv[0]; f0.u[1] = wv[1]; f0.u[2] = wv[2]; f0.u[3] = wv[3];
            f1.u[0] = wv[4]; f1.u[1] = wv[5]; f1.u[2] = wv[6]; f1.u[3] = wv[7];
            __builtin_amdgcn_s_setprio(1);
#pragma unroll
            for (int dt = 0; dt < 2; ++dt) {
                const short8 v0 = *(const short8*)(Vb + (dt * 32 + l31) * 128 +
                                                   (((s * 2 + 0) * 32 + hi * 16) ^ swz));
                oacc[dt] = __builtin_amdgcn_mfma_f32_32x32x16_bf16(v0, f0.s8, oacc[dt], 0, 0, 0);
                const short8 v1 = *(const short8*)(Vb + (dt * 32 + l31) * 128 +
                                                   (((s * 2 + 1) * 32 + hi * 16) ^ swz));
                oacc[dt] = __builtin_amdgcn_mfma_f32_32x32x16_bf16(v1, f1.s8, oacc[dt], 0, 0, 0);
            }
            __builtin_amdgcn_s_setprio(0);
        }
        __syncthreads();
    }

    const float inv = 1.0f / lr;
    char* outp = (char*)aout + ((size_t)(b * 2048 + q0 + l31) * 1024 + h * 64) * 2;
#pragma unroll
    for (int dt = 0; dt < 2; ++dt)
#pragma unroll
        for (int rg = 0; rg < 4; ++rg) {
            u32x2 pkd;
            pkd[0] = cvtpk(oacc[dt][rg * 4 + 0] * inv, oacc[dt][rg * 4 + 1] * inv);
            pkd[1] = cvtpk(oacc[dt][rg * 4 + 2] * inv, oacc[dt][rg * 4 + 3] * inv);
            *(u32x2*)(outp + (size_t)(dt * 32 + rg * 8 + hi * 4) * 2) = pkd;
        }
}

extern "C" void kernel_launch(void* const* d_in, const int* in_sizes, int n_in,
                              void* d_out, int out_size, void* d_ws, size_t ws_size,
                              hipStream_t stream) {
    const float* x      = (const float*)d_in[0];
    const float* ps     = (const float*)d_in[1];
    const float* qkv_w  = (const float*)d_in[2];
    const float* qkv_b  = (const float*)d_in[3];
    const float* proj_w = (const float*)d_in[4];
    const float* proj_b = (const float*)d_in[5];
    const float* pw     = (const float*)d_in[6];
    float* out = (float*)d_out;
    char* ws = (char*)d_ws;

    unsigned short* x_bf    = (unsigned short*)(ws);                   // 8 MB (reused as attn_bf)
    unsigned short* w1_bf   = (unsigned short*)(ws + (8u  << 20));     // 6 MB
    unsigned short* wp_bf   = (unsigned short*)(ws + (14u << 20));     // 2 MB
    unsigned short* qb      = (unsigned short*)(ws + (16u << 20));     // 8 MB
    unsigned short* kb      = (unsigned short*)(ws + (24u << 20));     // 8 MB
    unsigned short* vtb     = (unsigned short*)(ws + (32u << 20));     // 8 MB
    unsigned short* attn_bf = x_bf;

    cvt_bf16_kernel<<<4096, 256, 0, stream>>>(x,      x_bf,  1048576);
    cvt_bf16_kernel<<<3072, 256, 0, stream>>>(qkv_w,  w1_bf, 786432);
    cvt_bf16_kernel<<<1024, 256, 0, stream>>>(proj_w, wp_bf, 262144);

    gemm_qkv<<<dim3(16, 12), 512, 0, stream>>>(x_bf, w1_bf, qkv_b, ps, pw, qb, kb, vtb);
    attn_kernel<<<dim3(16, 32), 256, 0, stream>>>(qb, kb, vtb, attn_bf);
    gemm_proj<<<dim3(32, 8), 256, 0, stream>>>(attn_bf, wp_bf, proj_b, out);
}

// Round 7
// 111.866 us; speedup vs baseline: 1.1972x; 1.1972x over previous
//
#include <hip/hip_runtime.h>
#include <stdint.h>

#define NUM_H 16
#define HD    64
#define CDIM  1024
#define NSEQ  2048
#define NBATCH 2
#define LOG2E 1.4426950408889634f

typedef __attribute__((ext_vector_type(8))) short short8;
typedef __attribute__((ext_vector_type(4))) float f32x4;
typedef __attribute__((ext_vector_type(16))) float f32x16;
typedef __attribute__((ext_vector_type(4))) unsigned short ushort4v;
typedef __attribute__((ext_vector_type(4))) float float4v;
typedef __attribute__((ext_vector_type(2))) unsigned int u32x2;

__device__ __forceinline__ unsigned short f2bf(float f) {
    unsigned int u = __builtin_bit_cast(unsigned int, f);
    unsigned int r = u + 0x7fffu + ((u >> 16) & 1u);
    return (unsigned short)(r >> 16);
}

__device__ __forceinline__ unsigned int cvtpk(float a, float b) {
    unsigned int r;
    asm("v_cvt_pk_bf16_f32 %0, %1, %2" : "=v"(r) : "v"(a), "v"(b));
    return r;
}

__device__ __forceinline__ void plswap(unsigned int &a, unsigned int &b) {
    asm("v_permlane32_swap_b32 %0, %1" : "+v"(a), "+v"(b));
}

// global -> LDS async copy, 16B per lane. LDS dest is wave-uniform base + lane*16.
__device__ __forceinline__ void gload_lds16(const void* g, const void* l) {
    __builtin_amdgcn_global_load_lds(
        (const __attribute__((address_space(1))) unsigned int*)(unsigned long long)(uintptr_t)g,
        (__attribute__((address_space(3))) unsigned int*)(unsigned int)(uintptr_t)l,
        16, 0, 0);
}

__global__ void cvt_bf16_kernel(const float* __restrict__ in,
                                unsigned short* __restrict__ out, int n4) {
    int i = blockIdx.x * blockDim.x + threadIdx.x;
    if (i < n4) {
        float4v v = *(const float4v*)(in + (size_t)i * 4);
        ushort4v o;
        o[0] = f2bf(v[0]); o[1] = f2bf(v[1]); o[2] = f2bf(v[2]); o[3] = f2bf(v[3]);
        *(ushort4v*)(out + (size_t)i * 4) = o;
    }
}

// ---------------- GEMM1: qkv = x @ qkv_w^T + b : 256x256 8-phase (T3+T4) ----------------
// K-loop identical to R6 (verified correct). NEW: V-blocks (bn>=8) transpose their
// 256x256 tile through the 128KB LDS (free after the loop) and store vtb with
// 512B-contiguous coalesced writes — removes the 2B/4KB-stride scatter + its
// write-allocate FETCH amplification. Q/K keep the direct (32B-chunk) path.
// K output is PRE-SCALED by 0.125*(1+0.2*pw[h]*ps[b])*LOG2E.
__global__ __launch_bounds__(512, 2) void gemm_qkv(
    const unsigned short* __restrict__ A,   // x_bf  [4096][1024]
    const unsigned short* __restrict__ Bw,  // w1_bf [3072][1024]
    const float* __restrict__ bias,         // qkv_b [3072]
    const float* __restrict__ ps,           // phase_signal [2]
    const float* __restrict__ pw,           // phase_weight [16]
    unsigned short* __restrict__ qb,        // [B,H,N,D]
    unsigned short* __restrict__ kb,        // [B,H,N,D]  (pre-scaled)
    unsigned short* __restrict__ vtb)       // [B,H,D,N]  (transposed V)
{
    __shared__ unsigned short lds[2][2][2][128][64];  // [buf][A/B][half][row][col] = 128 KB

    const int tid = threadIdx.x;
    const int wid = tid >> 6;            // 0..7
    const int lane = tid & 63;
    const int l15 = lane & 15, l4 = lane >> 4;
    const int wave_m = wid >> 2, wave_n = wid & 3;

    const int bm = blockIdx.x;           // 16
    const int bn = blockIdx.y;           // 12

    f32x4 acc[8][4];
    const f32x4 zero4 = {0.f, 0.f, 0.f, 0.f};
#pragma unroll
    for (int m = 0; m < 8; ++m)
#pragma unroll
        for (int n = 0; n < 4; ++n) acc[m][n] = zero4;

    // staging lane geometry: 8 rows x 8 slots per load instr, inverse-swizzled source
    const int jr = lane >> 3;
    const int jc = ((lane & 7) ^ jr) << 4;
    const char* aB = (const char*)A  + (size_t)(bm * 256) * 2048;
    const char* bB = (const char*)Bw + (size_t)(bn * 256) * 2048;

    // half-tile stage: which: 0=A-half0, 1=A-half1, 2=B-half0, 3=B-half1
    auto stageH = [&](int t, int which) {
        const int buf = t & 1;
        const int op = which >> 1, hf = which & 1;
        const char* src = (op == 0) ? aB : bB;
        const int rowb = hf * 128 + wid * 16;
        const size_t k0b = (size_t)t * 128;
        char* dst = (char*)&lds[buf][op][hf][wid * 16][0];
#pragma unroll
        for (int i = 0; i < 2; ++i)
            gload_lds16(src + (size_t)(rowb + i * 8 + jr) * 2048 + k0b + jc,
                        dst + i * 1024);
    };

    const int swz = (l15 & 7) << 4;
    auto rdA = [&](int buf, int mq, int mp, int kk) -> short8 {
        return *(const short8*)((const char*)&lds[buf][0][wave_m][mq * 64 + mp * 16 + l15][0]
                                + ((kk * 64 + l4 * 16) ^ swz));
    };
    auto rdB = [&](int buf, int nq, int np, int kk) -> short8 {
        const int br = wave_n * 64 + nq * 32 + np * 16 + l15;
        return *(const short8*)((const char*)&lds[buf][1][br >> 7][br & 127][0]
                                + ((kk * 64 + l4 * 16) ^ swz));
    };

    // prologue: tile 0 (8 loads, oldest) + tile 1 (8 loads); vmcnt(8) = tile 0 landed
    stageH(0, 0); stageH(0, 1); stageH(0, 2); stageH(0, 3);
    stageH(1, 2); stageH(1, 3); stageH(1, 0); stageH(1, 1);
    asm volatile("s_waitcnt vmcnt(8)" ::: "memory");
    __builtin_amdgcn_s_barrier();

    for (int t = 0; t < 16; ++t) {
        const int buf = t & 1;
        short8 af[4][2], bf[2][2][2];

        // ---- phase 0: quadrant (mq=0, nq=0); no stage
#pragma unroll
        for (int mp = 0; mp < 4; ++mp) {
            af[mp][0] = rdA(buf, 0, mp, 0); af[mp][1] = rdA(buf, 0, mp, 1);
        }
#pragma unroll
        for (int np = 0; np < 2; ++np) {
            bf[0][np][0] = rdB(buf, 0, np, 0); bf[0][np][1] = rdB(buf, 0, np, 1);
        }
        __builtin_amdgcn_s_barrier();
        __builtin_amdgcn_s_setprio(1);
#pragma unroll
        for (int mp = 0; mp < 4; ++mp)
#pragma unroll
            for (int np = 0; np < 2; ++np)
#pragma unroll
                for (int kk = 0; kk < 2; ++kk)
                    acc[mp][np] = __builtin_amdgcn_mfma_f32_16x16x32_bf16(
                        af[mp][kk], bf[0][np][kk], acc[mp][np], 0, 0, 0);
        __builtin_amdgcn_s_setprio(0);
        __builtin_amdgcn_s_barrier();

        // ---- phase 1: (0,1); stage H(t+2, B-half0) (B0 reads finished at phase 0)
#pragma unroll
        for (int np = 0; np < 2; ++np) {
            bf[1][np][0] = rdB(buf, 1, np, 0); bf[1][np][1] = rdB(buf, 1, np, 1);
        }
        if (t < 14) stageH(t + 2, 2);
        __builtin_amdgcn_s_barrier();
        __builtin_amdgcn_s_setprio(1);
#pragma unroll
        for (int mp = 0; mp < 4; ++mp)
#pragma unroll
            for (int np = 0; np < 2; ++np)
#pragma unroll
                for (int kk = 0; kk < 2; ++kk)
                    acc[mp][2 + np] = __builtin_amdgcn_mfma_f32_16x16x32_bf16(
                        af[mp][kk], bf[1][np][kk], acc[mp][2 + np], 0, 0, 0);
        __builtin_amdgcn_s_setprio(0);
        __builtin_amdgcn_s_barrier();

        // ---- phase 2: (1,0); stage H(t+2, B-half1) (B1 reads finished at phase 1)
#pragma unroll
        for (int mp = 0; mp < 4; ++mp) {
            af[mp][0] = rdA(buf, 1, mp, 0); af[mp][1] = rdA(buf, 1, mp, 1);
        }
        if (t < 14) stageH(t + 2, 3);
        __builtin_amdgcn_s_barrier();
        __builtin_amdgcn_s_setprio(1);
#pragma unroll
        for (int mp = 0; mp < 4; ++mp)
#pragma unroll
            for (int np = 0; np < 2; ++np)
#pragma unroll
                for (int kk = 0; kk < 2; ++kk)
                    acc[4 + mp][np] = __builtin_amdgcn_mfma_f32_16x16x32_bf16(
                        af[mp][kk], bf[0][np][kk], acc[4 + mp][np], 0, 0, 0);
        __builtin_amdgcn_s_setprio(0);
        __builtin_amdgcn_s_barrier();

        // ---- phase 3: (1,1); stage H(t+2, A-half0+A-half1) (A reads finished at phase 2);
        //      counted vmcnt(8) at tile boundary = tile t+1 landed, t+2 in flight
        if (t < 14) { stageH(t + 2, 0); stageH(t + 2, 1); }
        __builtin_amdgcn_s_barrier();
        __builtin_amdgcn_s_setprio(1);
#pragma unroll
        for (int mp = 0; mp < 4; ++mp)
#pragma unroll
            for (int np = 0; np < 2; ++np)
#pragma unroll
                for (int kk = 0; kk < 2; ++kk)
                    acc[4 + mp][2 + np] = __builtin_amdgcn_mfma_f32_16x16x32_bf16(
                        af[mp][kk], bf[1][np][kk], acc[4 + mp][2 + np], 0, 0, 0);
        __builtin_amdgcn_s_setprio(0);
        if (t < 14)       { asm volatile("s_waitcnt vmcnt(8)" ::: "memory"); }
        else if (t == 14) { asm volatile("s_waitcnt vmcnt(0)" ::: "memory"); }
        __builtin_amdgcn_s_barrier();
    }

    // ---------------- epilogue ----------------
    const int row_base = bm * 256 + wave_m * 128;
    const int col_base = bn * 256 + wave_n * 64;
    const int t3b = bn >> 2;   // 0=Q, 1=K, 2=V (256-col tiles align with 1024 boundaries)
    const float ps0 = ps[0], ps1 = ps[1];

    if (t3b < 2) {
        unsigned short* dstb = (t3b == 0) ? qb : kb;
#pragma unroll
        for (int n = 0; n < 4; ++n) {
            const int col3 = col_base + n * 16 + l15;
            const float bv = bias[col3];
            const int hh = (col3 >> 6) & 15;
            const int dd = col3 & 63;
            float kf0 = 1.f, kf1 = 1.f;
            if (t3b == 1) {
                const float base = 0.125f * LOG2E;
                const float pwh = pw[hh];
                kf0 = base * (1.f + 0.2f * pwh * ps0);
                kf1 = base * (1.f + 0.2f * pwh * ps1);
            }
#pragma unroll
            for (int m = 0; m < 8; ++m) {
#pragma unroll
                for (int r = 0; r < 4; ++r) {
                    const int row = row_base + m * 16 + l4 * 4 + r;
                    const int bb = row >> 11, nn = row & 2047;
                    const size_t bh = (size_t)(bb * 16 + hh);
                    float v = acc[m][n][r] + bv;
                    if (t3b == 1) v *= (bb == 0) ? kf0 : kf1;
                    dstb[(bh * 2048 + nn) * 64 + dd] = f2bf(v);
                }
            }
        }
    } else {
        // V: transpose the 256x256 tile through LDS (reuse the 128KB staging buffer).
        // Write: byte = col*512 + (row*2 ^ ((col&15)<<4))  [bijective per-col row swizzle]
        // Read chunk c of col returns rows c*8..c*8+7 in order -> coalesced 512B stores.
        unsigned short* tb = &lds[0][0][0][0][0];
        __syncthreads();   // all K-loop LDS reads retired (post final barrier; belt&braces)
#pragma unroll
        for (int n = 0; n < 4; ++n) {
            const int col = wave_n * 64 + n * 16 + l15;          // 0..255 within tile
            const float bv = bias[col_base + n * 16 + l15];
            const int swzc = (col & 15) << 4;
#pragma unroll
            for (int m = 0; m < 8; ++m) {
#pragma unroll
                for (int r = 0; r < 4; ++r) {
                    const int row = wave_m * 128 + m * 16 + l4 * 4 + r;   // 0..255
                    *(unsigned short*)((char*)tb + col * 512 + ((row * 2) ^ swzc)) =
                        f2bf(acc[m][n][r] + bv);
                }
            }
        }
        __syncthreads();
        const int bb = bm >> 3;                     // batch of this row-block
        const size_t ncol0 = (size_t)(bm & 7) * 256;
#pragma unroll
        for (int i = 0; i < 16; ++i) {
            const int col = i * 16 + (tid >> 5);    // 0..255
            const int chunk = tid & 31;             // 16B chunk within 512B row
            const short8 v = *(const short8*)((const char*)tb + col * 512 +
                                              ((chunk * 16) ^ ((col & 15) << 4)));
            const int hh = (bn & 3) * 4 + (col >> 6);
            const int dd = col & 63;
            *(short8*)(vtb + ((size_t)(bb * 16 + hh) * 64 + dd) * 2048 + ncol0 + chunk * 8) = v;
        }
    }
}

// ---------------- GEMM2: out = attn @ proj_w^T + b (fp32 out) ----------------
// 128^2 2-phase dbuf; NATURAL block order (XCD = bm%8 partitions A cleanly).
__global__ __launch_bounds__(256, 2) void gemm_proj(
    const unsigned short* __restrict__ A,   // attn_bf [4096][1024]
    const unsigned short* __restrict__ Bw,  // wp_bf   [1024][1024]
    const float* __restrict__ bias,         // proj_b  [1024]
    float* __restrict__ out)                // [4096][1024] fp32
{
    __shared__ unsigned short As[2][128 * 64];
    __shared__ unsigned short Bs[2][128 * 64];
    const int tid = threadIdx.x;
    const int wid = tid >> 6;
    const int lane = tid & 63;
    const int l15 = lane & 15, l4 = lane >> 4;
    const int bm = blockIdx.x, bn = blockIdx.y;
    const int wr = wid >> 1, wc = wid & 1;

    f32x4 acc[4][4];
    const f32x4 zero4 = {0.f, 0.f, 0.f, 0.f};
#pragma unroll
    for (int m = 0; m < 4; ++m)
#pragma unroll
        for (int n = 0; n < 4; ++n) acc[m][n] = zero4;

    const int jr = lane >> 3;
    const int jc = ((lane & 7) ^ jr) << 4;
    const char* aB = (const char*)A  + (size_t)(bm * 128) * 2048;
    const char* bB = (const char*)Bw + (size_t)(bn * 128) * 2048;

    auto stage = [&](int buf, int k0) {
#pragma unroll
        for (int i = 0; i < 4; ++i) {
            const int rowb = wid * 32 + i * 8;
            gload_lds16(aB + (size_t)(rowb + jr) * 2048 + k0 * 2 + jc,
                        (const char*)&As[buf][0] + rowb * 128);
            gload_lds16(bB + (size_t)(rowb + jr) * 2048 + k0 * 2 + jc,
                        (const char*)&Bs[buf][0] + rowb * 128);
        }
    };

    const int swz = (l15 & 7) << 4;

    stage(0, 0);
    for (int it = 0; it < 16; ++it) {
        const int buf = it & 1;
        __syncthreads();
        if (it < 15) stage(buf ^ 1, (it + 1) * 64);
#pragma unroll
        for (int kk = 0; kk < 2; ++kk) {
            short8 a[4], b[4];
#pragma unroll
            for (int m = 0; m < 4; ++m)
                a[m] = *(const short8*)((const char*)&As[buf][0] +
                        (wr * 64 + m * 16 + l15) * 128 + ((kk * 64 + l4 * 16) ^ swz));
#pragma unroll
            for (int n = 0; n < 4; ++n)
                b[n] = *(const short8*)((const char*)&Bs[buf][0] +
                        (wc * 64 + n * 16 + l15) * 128 + ((kk * 64 + l4 * 16) ^ swz));
            __builtin_amdgcn_s_setprio(1);
#pragma unroll
            for (int m = 0; m < 4; ++m)
#pragma unroll
                for (int n = 0; n < 4; ++n)
                    acc[m][n] = __builtin_amdgcn_mfma_f32_16x16x32_bf16(a[m], b[n], acc[m][n], 0, 0, 0);
            __builtin_amdgcn_s_setprio(0);
        }
    }

    const int row_base = bm * 128 + wr * 64;
    const int col_base = bn * 128 + wc * 64;
#pragma unroll
    for (int n = 0; n < 4; ++n) {
        const int col = col_base + n * 16 + l15;
        const float bv = bias[col];
#pragma unroll
        for (int m = 0; m < 4; ++m) {
#pragma unroll
            for (int r = 0; r < 4; ++r) {
                const int row = row_base + m * 16 + l4 * 4 + r;
                out[(size_t)row * 1024 + col] = acc[m][n][r] + bv;
            }
        }
    }
}

// ---------------- Flash attention, swapped-QK^T, STATIC-SHIFT softmax ----------------
__global__ __launch_bounds__(256, 2) void attn_kernel(
    const unsigned short* __restrict__ qb,   // [B,H,N,D]
    const unsigned short* __restrict__ kb,   // [B,H,N,D] pre-scaled
    const unsigned short* __restrict__ vtb,  // [B,H,D,N]
    unsigned short* __restrict__ aout)       // [B*N][C] bf16
{
    __shared__ unsigned short KVs[2][2][64 * 64];   // [buf][K/V][row*64 + col] = 32 KB

    const int tid = threadIdx.x;
    const int w = tid >> 6;
    const int l = tid & 63;
    const int l31 = l & 31;
    const int hi = l >> 5;

    // T1: bijective XCD remap (nwg=512, 64/XCD): 16 q-tiles of a bh stay on one XCD
    const int bid = blockIdx.y * 16 + blockIdx.x;
    const int wg = (bid & 7) * 64 + (bid >> 3);
    const int bh = wg >> 4;
    const int b = bh >> 4, h = bh & 15;
    const int q0 = (wg & 15) * 128 + w * 32;

    const char* qg = (const char*)(qb + (size_t)bh * 2048 * 64);
    const char* kg = (const char*)(kb + (size_t)bh * 2048 * 64);
    const char* vg = (const char*)(vtb + (size_t)bh * 64 * 2048);

    short8 qf[4];
#pragma unroll
    for (int t = 0; t < 4; ++t)
        qf[t] = *(const short8*)(qg + (size_t)(q0 + l31) * 128 + t * 32 + hi * 16);

    f32x16 oacc[2];
#pragma unroll
    for (int dt = 0; dt < 2; ++dt)
#pragma unroll
        for (int r = 0; r < 16; ++r) oacc[dt][r] = 0.f;
    float lr = 0.f;

    const int jr = l >> 3;
    const int jc = ((l & 7) ^ jr) << 4;
    auto stage = [&](int buf, int kv0) {
#pragma unroll
        for (int i = 0; i < 2; ++i) {
            const int row = w * 16 + i * 8;
            gload_lds16(kg + (size_t)(kv0 + row + jr) * 128 + jc,
                        (const char*)&KVs[buf][0][0] + row * 128);
            gload_lds16(vg + (size_t)(row + jr) * 4096 + (size_t)kv0 * 2 + jc,
                        (const char*)&KVs[buf][1][0] + row * 128);
        }
    };

    stage(0, 0);
    __syncthreads();

    const int swz = (l31 & 7) << 4;

    for (int it = 0; it < 32; ++it) {
        const int buf = it & 1;
        if (it < 31) stage(buf ^ 1, (it + 1) * 64);

        const char* Kb = (const char*)&KVs[buf][0][0];
        const char* Vb = (const char*)&KVs[buf][1][0];

        f32x16 sa[2];
        __builtin_amdgcn_s_setprio(1);
#pragma unroll
        for (int s = 0; s < 2; ++s) {
#pragma unroll
            for (int r = 0; r < 16; ++r) sa[s][r] = 0.f;
#pragma unroll
            for (int t = 0; t < 4; ++t) {
                const short8 kf = *(const short8*)(Kb + (s * 32 + l31) * 128 +
                                                   ((t * 32 + hi * 16) ^ swz));
                sa[s] = __builtin_amdgcn_mfma_f32_32x32x16_bf16(kf, qf[t], sa[s], 0, 0, 0);
            }
        }
        __builtin_amdgcn_s_setprio(0);

        // static-shift softmax: P = 2^(s-20); uniform scale cancels in O/lr
#pragma unroll
        for (int s = 0; s < 2; ++s)
#pragma unroll
            for (int r = 0; r < 16; ++r)
                sa[s][r] = __builtin_amdgcn_exp2f(sa[s][r] - 20.0f);

        float ts[16];
#pragma unroll
        for (int r = 0; r < 16; ++r) ts[r] = sa[0][r] + sa[1][r];
#pragma unroll
        for (int d = 8; d >= 1; d >>= 1)
#pragma unroll
            for (int r = 0; r < 8; ++r)
                if (r < d) ts[r] += ts[r + d];
        lr += ts[0] + __shfl_xor(ts[0], 32);

#pragma unroll
        for (int s = 0; s < 2; ++s) {
            unsigned int wv[8];
#pragma unroll
            for (int g = 0; g < 8; ++g)
                wv[g] = cvtpk(sa[s][g * 2], sa[s][g * 2 + 1]);
            plswap(wv[0], wv[2]); plswap(wv[1], wv[3]);
            plswap(wv[4], wv[6]); plswap(wv[5], wv[7]);
            union { unsigned int u[4]; short8 s8; } f0, f1;
            f0.u[0] = wv[0]; f0.u[1] = wv[1]; f0.u[2] = wv[2]; f0.u[3] = wv[3];
            f1.u[0] = wv[4]; f1.u[1] = wv[5]; f1.u[2] = wv[6]; f1.u[3] = wv[7];
            __builtin_amdgcn_s_setprio(1);
#pragma unroll
            for (int dt = 0; dt < 2; ++dt) {
                const short8 v0 = *(const short8*)(Vb + (dt * 32 + l31) * 128 +
                                                   (((s * 2 + 0) * 32 + hi * 16) ^ swz));
                oacc[dt] = __builtin_amdgcn_mfma_f32_32x32x16_bf16(v0, f0.s8, oacc[dt], 0, 0, 0);
                const short8 v1 = *(const short8*)(Vb + (dt * 32 + l31) * 128 +
                                                   (((s * 2 + 1) * 32 + hi * 16) ^ swz));
                oacc[dt] = __builtin_amdgcn_mfma_f32_32x32x16_bf16(v1, f1.s8, oacc[dt], 0, 0, 0);
            }
            __builtin_amdgcn_s_setprio(0);
        }
        __syncthreads();
    }

    const float inv = 1.0f / lr;
    char* outp = (char*)aout + ((size_t)(b * 2048 + q0 + l31) * 1024 + h * 64) * 2;
#pragma unroll
    for (int dt = 0; dt < 2; ++dt)
#pragma unroll
        for (int rg = 0; rg < 4; ++rg) {
            u32x2 pkd;
            pkd[0] = cvtpk(oacc[dt][rg * 4 + 0] * inv, oacc[dt][rg * 4 + 1] * inv);
            pkd[1] = cvtpk(oacc[dt][rg * 4 + 2] * inv, oacc[dt][rg * 4 + 3] * inv);
            *(u32x2*)(outp + (size_t)(dt * 32 + rg * 8 + hi * 4) * 2) = pkd;
        }
}

extern "C" void kernel_launch(void* const* d_in, const int* in_sizes, int n_in,
                              void* d_out, int out_size, void* d_ws, size_t ws_size,
                              hipStream_t stream) {
    const float* x      = (const float*)d_in[0];
    const float* ps     = (const float*)d_in[1];
    const float* qkv_w  = (const float*)d_in[2];
    const float* qkv_b  = (const float*)d_in[3];
    const float* proj_w = (const float*)d_in[4];
    const float* proj_b = (const float*)d_in[5];
    const float* pw     = (const float*)d_in[6];
    float* out = (float*)d_out;
    char* ws = (char*)d_ws;

    unsigned short* x_bf    = (unsigned short*)(ws);                   // 8 MB (reused as attn_bf)
    unsigned short* w1_bf   = (unsigned short*)(ws + (8u  << 20));     // 6 MB
    unsigned short* wp_bf   = (unsigned short*)(ws + (14u << 20));     // 2 MB
    unsigned short* qb      = (unsigned short*)(ws + (16u << 20));     // 8 MB
    unsigned short* kb      = (unsigned short*)(ws + (24u << 20));     // 8 MB
    unsigned short* vtb     = (unsigned short*)(ws + (32u << 20));     // 8 MB
    unsigned short* attn_bf = x_bf;

    cvt_bf16_kernel<<<4096, 256, 0, stream>>>(x,      x_bf,  1048576);
    cvt_bf16_kernel<<<3072, 256, 0, stream>>>(qkv_w,  w1_bf, 786432);
    cvt_bf16_kernel<<<1024, 256, 0, stream>>>(proj_w, wp_bf, 262144);

    gemm_qkv<<<dim3(16, 12), 512, 0, stream>>>(x_bf, w1_bf, qkv_b, ps, pw, qb, kb, vtb);
    attn_kernel<<<dim3(16, 32), 256, 0, stream>>>(qb, kb, vtb, attn_bf);
    gemm_proj<<<dim3(32, 8), 256, 0, stream>>>(attn_bf, wp_bf, proj_b, out);
}

// Round 8
// 110.127 us; speedup vs baseline: 1.2161x; 1.0158x over previous
//
#include <hip/hip_runtime.h>
#include <stdint.h>

#define NUM_H 16
#define HD    64
#define CDIM  1024
#define NSEQ  2048
#define NBATCH 2
#define LOG2E 1.4426950408889634f

typedef __attribute__((ext_vector_type(8))) short short8;
typedef __attribute__((ext_vector_type(4))) float f32x4;
typedef __attribute__((ext_vector_type(16))) float f32x16;
typedef __attribute__((ext_vector_type(4))) unsigned short ushort4v;
typedef __attribute__((ext_vector_type(4))) float float4v;
typedef __attribute__((ext_vector_type(2))) unsigned int u32x2;

__device__ __forceinline__ unsigned short f2bf(float f) {
    unsigned int u = __builtin_bit_cast(unsigned int, f);
    unsigned int r = u + 0x7fffu + ((u >> 16) & 1u);
    return (unsigned short)(r >> 16);
}

__device__ __forceinline__ unsigned int cvtpk(float a, float b) {
    unsigned int r;
    asm("v_cvt_pk_bf16_f32 %0, %1, %2" : "=v"(r) : "v"(a), "v"(b));
    return r;
}

__device__ __forceinline__ void plswap(unsigned int &a, unsigned int &b) {
    asm("v_permlane32_swap_b32 %0, %1" : "+v"(a), "+v"(b));
}

// global -> LDS async copy, 16B per lane. LDS dest is wave-uniform base + lane*16.
__device__ __forceinline__ void gload_lds16(const void* g, const void* l) {
    __builtin_amdgcn_global_load_lds(
        (const __attribute__((address_space(1))) unsigned int*)(unsigned long long)(uintptr_t)g,
        (__attribute__((address_space(3))) unsigned int*)(unsigned int)(uintptr_t)l,
        16, 0, 0);
}

__global__ void cvt_bf16_kernel(const float* __restrict__ in,
                                unsigned short* __restrict__ out, int n4) {
    int i = blockIdx.x * blockDim.x + threadIdx.x;
    if (i < n4) {
        float4v v = *(const float4v*)(in + (size_t)i * 4);
        ushort4v o;
        o[0] = f2bf(v[0]); o[1] = f2bf(v[1]); o[2] = f2bf(v[2]); o[3] = f2bf(v[3]);
        *(ushort4v*)(out + (size_t)i * 4) = o;
    }
}

// ---------------- GEMM1: qkv = x @ qkv_w^T + b : 256x256 8-phase (T3+T4) ----------------
// K-loop identical to R6/R7 (verified). Epilogue: ALL outputs re-layout through the
// 128KB LDS (free after the loop):
//   Q  -> standard [B,H,N,D] via full-128B-line coalesced stores (no write-allocate RMW)
//   K  -> attn fragment order kfrag[bh][T][frag s*4+t][lane hi*32+l31][8 bf16], PRE-SCALED
//         (element = K[T*64 + s*32 + l31][d = t*16 + hi*8 + e])
//   V  -> attn fragment order vfrag[bh][T][frag dt*4+ks][lane hi*32+l31][8 bf16]
//         (element = V^T[d = dt*32 + l31][kv = T*64 + ks*16 + hi*8 + e])
// attn then stages 1KB-contiguous and reads LDS lane-linear: zero bank conflicts.
__global__ __launch_bounds__(512, 2) void gemm_qkv(
    const unsigned short* __restrict__ A,   // x_bf  [4096][1024]
    const unsigned short* __restrict__ Bw,  // w1_bf [3072][1024]
    const float* __restrict__ bias,         // qkv_b [3072]
    const float* __restrict__ ps,           // phase_signal [2]
    const float* __restrict__ pw,           // phase_weight [16]
    unsigned short* __restrict__ qb,        // [B,H,N,D]
    unsigned short* __restrict__ kfrag,     // [bh][32][8][64][8]  (pre-scaled)
    unsigned short* __restrict__ vfrag)     // [bh][32][8][64][8]
{
    __shared__ unsigned short lds[2][2][2][128][64];  // [buf][A/B][half][row][col] = 128 KB

    const int tid = threadIdx.x;
    const int wid = tid >> 6;            // 0..7
    const int lane = tid & 63;
    const int l15 = lane & 15, l4 = lane >> 4;
    const int wave_m = wid >> 2, wave_n = wid & 3;

    const int bm = blockIdx.x;           // 16
    const int bn = blockIdx.y;           // 12

    f32x4 acc[8][4];
    const f32x4 zero4 = {0.f, 0.f, 0.f, 0.f};
#pragma unroll
    for (int m = 0; m < 8; ++m)
#pragma unroll
        for (int n = 0; n < 4; ++n) acc[m][n] = zero4;

    // staging lane geometry: 8 rows x 8 slots per load instr, inverse-swizzled source
    const int jr = lane >> 3;
    const int jc = ((lane & 7) ^ jr) << 4;
    const char* aB = (const char*)A  + (size_t)(bm * 256) * 2048;
    const char* bB = (const char*)Bw + (size_t)(bn * 256) * 2048;

    // half-tile stage: which: 0=A-half0, 1=A-half1, 2=B-half0, 3=B-half1
    auto stageH = [&](int t, int which) {
        const int buf = t & 1;
        const int op = which >> 1, hf = which & 1;
        const char* src = (op == 0) ? aB : bB;
        const int rowb = hf * 128 + wid * 16;
        const size_t k0b = (size_t)t * 128;
        char* dst = (char*)&lds[buf][op][hf][wid * 16][0];
#pragma unroll
        for (int i = 0; i < 2; ++i)
            gload_lds16(src + (size_t)(rowb + i * 8 + jr) * 2048 + k0b + jc,
                        dst + i * 1024);
    };

    const int swz = (l15 & 7) << 4;
    auto rdA = [&](int buf, int mq, int mp, int kk) -> short8 {
        return *(const short8*)((const char*)&lds[buf][0][wave_m][mq * 64 + mp * 16 + l15][0]
                                + ((kk * 64 + l4 * 16) ^ swz));
    };
    auto rdB = [&](int buf, int nq, int np, int kk) -> short8 {
        const int br = wave_n * 64 + nq * 32 + np * 16 + l15;
        return *(const short8*)((const char*)&lds[buf][1][br >> 7][br & 127][0]
                                + ((kk * 64 + l4 * 16) ^ swz));
    };

    // prologue: tile 0 (8 loads, oldest) + tile 1 (8 loads); vmcnt(8) = tile 0 landed
    stageH(0, 0); stageH(0, 1); stageH(0, 2); stageH(0, 3);
    stageH(1, 2); stageH(1, 3); stageH(1, 0); stageH(1, 1);
    asm volatile("s_waitcnt vmcnt(8)" ::: "memory");
    __builtin_amdgcn_s_barrier();

    for (int t = 0; t < 16; ++t) {
        const int buf = t & 1;
        short8 af[4][2], bf[2][2][2];

        // ---- phase 0: quadrant (mq=0, nq=0); no stage
#pragma unroll
        for (int mp = 0; mp < 4; ++mp) {
            af[mp][0] = rdA(buf, 0, mp, 0); af[mp][1] = rdA(buf, 0, mp, 1);
        }
#pragma unroll
        for (int np = 0; np < 2; ++np) {
            bf[0][np][0] = rdB(buf, 0, np, 0); bf[0][np][1] = rdB(buf, 0, np, 1);
        }
        __builtin_amdgcn_s_barrier();
        __builtin_amdgcn_s_setprio(1);
#pragma unroll
        for (int mp = 0; mp < 4; ++mp)
#pragma unroll
            for (int np = 0; np < 2; ++np)
#pragma unroll
                for (int kk = 0; kk < 2; ++kk)
                    acc[mp][np] = __builtin_amdgcn_mfma_f32_16x16x32_bf16(
                        af[mp][kk], bf[0][np][kk], acc[mp][np], 0, 0, 0);
        __builtin_amdgcn_s_setprio(0);
        __builtin_amdgcn_s_barrier();

        // ---- phase 1: (0,1); stage H(t+2, B-half0) (B0 reads finished at phase 0)
#pragma unroll
        for (int np = 0; np < 2; ++np) {
            bf[1][np][0] = rdB(buf, 1, np, 0); bf[1][np][1] = rdB(buf, 1, np, 1);
        }
        if (t < 14) stageH(t + 2, 2);
        __builtin_amdgcn_s_barrier();
        __builtin_amdgcn_s_setprio(1);
#pragma unroll
        for (int mp = 0; mp < 4; ++mp)
#pragma unroll
            for (int np = 0; np < 2; ++np)
#pragma unroll
                for (int kk = 0; kk < 2; ++kk)
                    acc[mp][2 + np] = __builtin_amdgcn_mfma_f32_16x16x32_bf16(
                        af[mp][kk], bf[1][np][kk], acc[mp][2 + np], 0, 0, 0);
        __builtin_amdgcn_s_setprio(0);
        __builtin_amdgcn_s_barrier();

        // ---- phase 2: (1,0); stage H(t+2, B-half1) (B1 reads finished at phase 1)
#pragma unroll
        for (int mp = 0; mp < 4; ++mp) {
            af[mp][0] = rdA(buf, 1, mp, 0); af[mp][1] = rdA(buf, 1, mp, 1);
        }
        if (t < 14) stageH(t + 2, 3);
        __builtin_amdgcn_s_barrier();
        __builtin_amdgcn_s_setprio(1);
#pragma unroll
        for (int mp = 0; mp < 4; ++mp)
#pragma unroll
            for (int np = 0; np < 2; ++np)
#pragma unroll
                for (int kk = 0; kk < 2; ++kk)
                    acc[4 + mp][np] = __builtin_amdgcn_mfma_f32_16x16x32_bf16(
                        af[mp][kk], bf[0][np][kk], acc[4 + mp][np], 0, 0, 0);
        __builtin_amdgcn_s_setprio(0);
        __builtin_amdgcn_s_barrier();

        // ---- phase 3: (1,1); stage H(t+2, A-half0+A-half1) (A reads finished at phase 2);
        //      counted vmcnt(8) at tile boundary = tile t+1 landed, t+2 in flight
        if (t < 14) { stageH(t + 2, 0); stageH(t + 2, 1); }
        __builtin_amdgcn_s_barrier();
        __builtin_amdgcn_s_setprio(1);
#pragma unroll
        for (int mp = 0; mp < 4; ++mp)
#pragma unroll
            for (int np = 0; np < 2; ++np)
#pragma unroll
                for (int kk = 0; kk < 2; ++kk)
                    acc[4 + mp][2 + np] = __builtin_amdgcn_mfma_f32_16x16x32_bf16(
                        af[mp][kk], bf[1][np][kk], acc[4 + mp][2 + np], 0, 0, 0);
        __builtin_amdgcn_s_setprio(0);
        if (t < 14)       { asm volatile("s_waitcnt vmcnt(8)" ::: "memory"); }
        else if (t == 14) { asm volatile("s_waitcnt vmcnt(0)" ::: "memory"); }
        __builtin_amdgcn_s_barrier();
    }

    // ---------------- epilogue: re-layout through LDS ----------------
    const int col_base = bn * 256 + wave_n * 64;
    const int t3b = bn >> 2;   // 0=Q, 1=K, 2=V
    const int bb = bm >> 3;
    const int nn0 = (bm & 7) * 256;
    char* tbc = (char*)&lds[0][0][0][0][0];

    __syncthreads();   // all K-loop LDS reads retired

    if (t3b == 0) {
        // Q image: [h'=wave_n][tt 0..255][d], byte = h'*32768 + tt*128 + ((d*2)^((tt&7)<<4))
#pragma unroll
        for (int n = 0; n < 4; ++n) {
            const int d = n * 16 + l15;
            const float bv = bias[col_base + n * 16 + l15];
#pragma unroll
            for (int m = 0; m < 8; ++m) {
#pragma unroll
                for (int r = 0; r < 4; ++r) {
                    const int tt = wave_m * 128 + m * 16 + l4 * 4 + r;
                    *(unsigned short*)(tbc + wave_n * 32768 + tt * 128 +
                                       ((d * 2) ^ ((tt & 7) << 4))) = f2bf(acc[m][n][r] + bv);
                }
            }
        }
        __syncthreads();
#pragma unroll
        for (int i = 0; i < 16; ++i) {
            const int hq = i >> 2, sub = i & 3;
            const int tt = sub * 64 + (tid >> 3);
            const int chunk = tid & 7;
            const short8 v = *(const short8*)(tbc + hq * 32768 + tt * 128 +
                                              ((chunk * 16) ^ ((tt & 7) << 4)));
            *(short8*)(qb + ((size_t)(bb * 16 + bn * 4 + hq) * 2048 + nn0 + tt) * 64 + chunk * 8) = v;
        }
    } else if (t3b == 1) {
        // K fragment image: [h'][ti][frag s*4+t][lane hi*32+l31][8], scaled
        const float ps0 = ps[0], ps1 = ps[1];
        const int hh = (bn - 4) * 4 + wave_n;
        const float kf = 0.125f * LOG2E *
                         (1.f + 0.2f * pw[hh] * ((bb == 0) ? ps0 : ps1));
#pragma unroll
        for (int n = 0; n < 4; ++n) {
            const int hi_ = l15 >> 3, e = l15 & 7;       // d = n*16 + l15 -> t=n
            const float bv = bias[col_base + n * 16 + l15];
#pragma unroll
            for (int m = 0; m < 8; ++m) {
#pragma unroll
                for (int r = 0; r < 4; ++r) {
                    const int tt = wave_m * 128 + m * 16 + l4 * 4 + r;
                    const int ti = tt >> 6, u = tt & 63;
                    const int s_ = u >> 5, l31_ = u & 31;
                    *(unsigned short*)(tbc + (((wave_n * 4 + ti) * 8 + s_ * 4 + n) << 10) +
                                       ((hi_ * 32 + l31_) << 4) + e * 2) =
                        f2bf((acc[m][n][r] + bv) * kf);
                }
            }
        }
        __syncthreads();
#pragma unroll
        for (int i = 0; i < 16; ++i) {
            const int hq = i >> 2, ti = i & 3;
            const short8 v = *(const short8*)(tbc + i * 8192 + tid * 16);
            *(short8*)(kfrag + ((size_t)(bb * 16 + (bn - 4) * 4 + hq) * 32 +
                                ((bm & 7) * 4 + ti)) * 4096 + tid * 8) = v;
        }
    } else {
        // V fragment image: [h'][ti][frag dt*4+ks][lane hi*32+(d&31)][8]
#pragma unroll
        for (int n = 0; n < 4; ++n) {
            const int d = n * 16 + l15;
            const int dt_ = n >> 1, l31_ = d & 31;
            const float bv = bias[col_base + n * 16 + l15];
#pragma unroll
            for (int m = 0; m < 8; ++m) {
#pragma unroll
                for (int r = 0; r < 4; ++r) {
                    const int tt = wave_m * 128 + m * 16 + l4 * 4 + r;
                    const int ti = tt >> 6, u = tt & 63;
                    const int ks = u >> 4, hi_ = (u >> 3) & 1, e = u & 7;
                    *(unsigned short*)(tbc + (((wave_n * 4 + ti) * 8 + dt_ * 4 + ks) << 10) +
                                       ((hi_ * 32 + l31_) << 4) + e * 2) =
                        f2bf(acc[m][n][r] + bv);
                }
            }
        }
        __syncthreads();
#pragma unroll
        for (int i = 0; i < 16; ++i) {
            const int hq = i >> 2, ti = i & 3;
            const short8 v = *(const short8*)(tbc + i * 8192 + tid * 16);
            *(short8*)(vfrag + ((size_t)(bb * 16 + (bn - 8) * 4 + hq) * 32 +
                                ((bm & 7) * 4 + ti)) * 4096 + tid * 8) = v;
        }
    }
}

// ---------------- GEMM2: out = attn @ proj_w^T + b (fp32 out) ----------------
// 128^2 2-phase dbuf; NATURAL block order (XCD = bm%8 partitions A cleanly).
__global__ __launch_bounds__(256, 2) void gemm_proj(
    const unsigned short* __restrict__ A,   // attn_bf [4096][1024]
    const unsigned short* __restrict__ Bw,  // wp_bf   [1024][1024]
    const float* __restrict__ bias,         // proj_b  [1024]
    float* __restrict__ out)                // [4096][1024] fp32
{
    __shared__ unsigned short As[2][128 * 64];
    __shared__ unsigned short Bs[2][128 * 64];
    const int tid = threadIdx.x;
    const int wid = tid >> 6;
    const int lane = tid & 63;
    const int l15 = lane & 15, l4 = lane >> 4;
    const int bm = blockIdx.x, bn = blockIdx.y;
    const int wr = wid >> 1, wc = wid & 1;

    f32x4 acc[4][4];
    const f32x4 zero4 = {0.f, 0.f, 0.f, 0.f};
#pragma unroll
    for (int m = 0; m < 4; ++m)
#pragma unroll
        for (int n = 0; n < 4; ++n) acc[m][n] = zero4;

    const int jr = lane >> 3;
    const int jc = ((lane & 7) ^ jr) << 4;
    const char* aB = (const char*)A  + (size_t)(bm * 128) * 2048;
    const char* bB = (const char*)Bw + (size_t)(bn * 128) * 2048;

    auto stage = [&](int buf, int k0) {
#pragma unroll
        for (int i = 0; i < 4; ++i) {
            const int rowb = wid * 32 + i * 8;
            gload_lds16(aB + (size_t)(rowb + jr) * 2048 + k0 * 2 + jc,
                        (const char*)&As[buf][0] + rowb * 128);
            gload_lds16(bB + (size_t)(rowb + jr) * 2048 + k0 * 2 + jc,
                        (const char*)&Bs[buf][0] + rowb * 128);
        }
    };

    const int swz = (l15 & 7) << 4;

    stage(0, 0);
    for (int it = 0; it < 16; ++it) {
        const int buf = it & 1;
        __syncthreads();
        if (it < 15) stage(buf ^ 1, (it + 1) * 64);
#pragma unroll
        for (int kk = 0; kk < 2; ++kk) {
            short8 a[4], b[4];
#pragma unroll
            for (int m = 0; m < 4; ++m)
                a[m] = *(const short8*)((const char*)&As[buf][0] +
                        (wr * 64 + m * 16 + l15) * 128 + ((kk * 64 + l4 * 16) ^ swz));
#pragma unroll
            for (int n = 0; n < 4; ++n)
                b[n] = *(const short8*)((const char*)&Bs[buf][0] +
                        (wc * 64 + n * 16 + l15) * 128 + ((kk * 64 + l4 * 16) ^ swz));
            __builtin_amdgcn_s_setprio(1);
#pragma unroll
            for (int m = 0; m < 4; ++m)
#pragma unroll
                for (int n = 0; n < 4; ++n)
                    acc[m][n] = __builtin_amdgcn_mfma_f32_16x16x32_bf16(a[m], b[n], acc[m][n], 0, 0, 0);
            __builtin_amdgcn_s_setprio(0);
        }
    }

    const int row_base = bm * 128 + wr * 64;
    const int col_base = bn * 128 + wc * 64;
#pragma unroll
    for (int n = 0; n < 4; ++n) {
        const int col = col_base + n * 16 + l15;
        const float bv = bias[col];
#pragma unroll
        for (int m = 0; m < 4; ++m) {
#pragma unroll
            for (int r = 0; r < 4; ++r) {
                const int row = row_base + m * 16 + l4 * 4 + r;
                out[(size_t)row * 1024 + col] = acc[m][n][r] + bv;
            }
        }
    }
}

// ---------------- Flash attention: fragment-ordered K/V, zero-conflict LDS ----------------
// 4 waves x 32 q-rows; KVBLK=64; swapped QK^T; static-shift softmax (K pre-scaled).
// Stage: 1KB-contiguous global_load_lds per (wave, frag); reads lane-linear.
__global__ __launch_bounds__(256, 2) void attn_kernel(
    const unsigned short* __restrict__ qb,     // [B,H,N,D]
    const unsigned short* __restrict__ kfrag,  // [bh][32][8][64][8] pre-scaled
    const unsigned short* __restrict__ vfrag,  // [bh][32][8][64][8]
    unsigned short* __restrict__ aout)         // [B*N][C] bf16
{
    __shared__ unsigned short KVs[2][2][4096];   // [buf][K/V][frag*512 + lane*8] = 32 KB

    const int tid = threadIdx.x;
    const int w = tid >> 6;
    const int l = tid & 63;
    const int l31 = l & 31;
    const int hi = l >> 5;

    // T1: bijective XCD remap (nwg=512, 64/XCD): 16 q-tiles of a bh stay on one XCD
    const int bid = blockIdx.y * 16 + blockIdx.x;
    const int wg = (bid & 7) * 64 + (bid >> 3);
    const int bh = wg >> 4;
    const int b = bh >> 4, h = bh & 15;
    const int q0 = (wg & 15) * 128 + w * 32;

    const char* qg = (const char*)(qb + (size_t)bh * 2048 * 64);
    const unsigned short* kg = kfrag + (size_t)bh * 32 * 4096;
    const unsigned short* vg = vfrag + (size_t)bh * 32 * 4096;

    short8 qf[4];
#pragma unroll
    for (int t = 0; t < 4; ++t)
        qf[t] = *(const short8*)(qg + (size_t)(q0 + l31) * 128 + t * 32 + hi * 16);

    f32x16 oacc[2];
#pragma unroll
    for (int dt = 0; dt < 2; ++dt)
#pragma unroll
        for (int r = 0; r < 16; ++r) oacc[dt][r] = 0.f;
    float lr = 0.f;

    // wave w stages frags 2w, 2w+1 of both K and V: contiguous 1KB per gload
    auto stage = [&](int buf, int T) {
#pragma unroll
        for (int i = 0; i < 2; ++i) {
            const int c = w * 2 + i;
            gload_lds16(kg + (size_t)T * 4096 + c * 512 + l * 8, &KVs[buf][0][c * 512]);
            gload_lds16(vg + (size_t)T * 4096 + c * 512 + l * 8, &KVs[buf][1][c * 512]);
        }
    };

    stage(0, 0);
    __syncthreads();

    for (int it = 0; it < 32; ++it) {
        const int buf = it & 1;
        if (it < 31) stage(buf ^ 1, it + 1);

        const unsigned short* Kb = &KVs[buf][0][0];
        const unsigned short* Vb = &KVs[buf][1][0];

        // S^T[kv][q] : lane holds q=l&31, kv = s*32 + (r&3)+8*(r>>2)+4*hi
        f32x16 sa[2];
        __builtin_amdgcn_s_setprio(1);
#pragma unroll
        for (int s = 0; s < 2; ++s) {
#pragma unroll
            for (int r = 0; r < 16; ++r) sa[s][r] = 0.f;
#pragma unroll
            for (int t = 0; t < 4; ++t) {
                const short8 kf = *(const short8*)(Kb + (s * 4 + t) * 512 + l * 8);
                sa[s] = __builtin_amdgcn_mfma_f32_32x32x16_bf16(kf, qf[t], sa[s], 0, 0, 0);
            }
        }
        __builtin_amdgcn_s_setprio(0);

        // static-shift softmax: P = 2^(s-20); uniform scale cancels in O/lr
#pragma unroll
        for (int s = 0; s < 2; ++s)
#pragma unroll
            for (int r = 0; r < 16; ++r)
                sa[s][r] = __builtin_amdgcn_exp2f(sa[s][r] - 20.0f);

        float ts[16];
#pragma unroll
        for (int r = 0; r < 16; ++r) ts[r] = sa[0][r] + sa[1][r];
#pragma unroll
        for (int d = 8; d >= 1; d >>= 1)
#pragma unroll
            for (int r = 0; r < 8; ++r)
                if (r < d) ts[r] += ts[r + d];
        lr += ts[0] + __shfl_xor(ts[0], 32);

        // P -> bf16 B-fragments (cvt_pk + permlane32_swap), then PV
#pragma unroll
        for (int s = 0; s < 2; ++s) {
            unsigned int wv[8];
#pragma unroll
            for (int g = 0; g < 8; ++g)
                wv[g] = cvtpk(sa[s][g * 2], sa[s][g * 2 + 1]);
            plswap(wv[0], wv[2]); plswap(wv[1], wv[3]);
            plswap(wv[4], wv[6]); plswap(wv[5], wv[7]);
            union { unsigned int u[4]; short8 s8; } f0, f1;
            f0.u[0] = wv[0]; f0.u[1] = wv[1]; f0.u[2] = wv[2]; f0.u[3] = wv[3];
            f1.u[0] = wv[4]; f1.u[1] = wv[5]; f1.u[2] = wv[6]; f1.u[3] = wv[7];
            __builtin_amdgcn_s_setprio(1);
#pragma unroll
            for (int dt = 0; dt < 2; ++dt) {
                const short8 v0 = *(const short8*)(Vb + (dt * 4 + s * 2 + 0) * 512 + l * 8);
                oacc[dt] = __builtin_amdgcn_mfma_f32_32x32x16_bf16(v0, f0.s8, oacc[dt], 0, 0, 0);
                const short8 v1 = *(const short8*)(Vb + (dt * 4 + s * 2 + 1) * 512 + l * 8);
                oacc[dt] = __builtin_amdgcn_mfma_f32_32x32x16_bf16(v1, f1.s8, oacc[dt], 0, 0, 0);
            }
            __builtin_amdgcn_s_setprio(0);
        }
        __syncthreads();   // drains vmcnt: next tile's stage complete; cur buf free
    }

    // epilogue: O^T lane holds q=l&31, d = dt*32 + (r&3)+8*(r>>2)+4*hi
    const float inv = 1.0f / lr;
    char* outp = (char*)aout + ((size_t)(b * 2048 + q0 + l31) * 1024 + h * 64) * 2;
#pragma unroll
    for (int dt = 0; dt < 2; ++dt)
#pragma unroll
        for (int rg = 0; rg < 4; ++rg) {
            u32x2 pkd;
            pkd[0] = cvtpk(oacc[dt][rg * 4 + 0] * inv, oacc[dt][rg * 4 + 1] * inv);
            pkd[1] = cvtpk(oacc[dt][rg * 4 + 2] * inv, oacc[dt][rg * 4 + 3] * inv);
            *(u32x2*)(outp + (size_t)(dt * 32 + rg * 8 + hi * 4) * 2) = pkd;
        }
}

extern "C" void kernel_launch(void* const* d_in, const int* in_sizes, int n_in,
                              void* d_out, int out_size, void* d_ws, size_t ws_size,
                              hipStream_t stream) {
    const float* x      = (const float*)d_in[0];
    const float* ps     = (const float*)d_in[1];
    const float* qkv_w  = (const float*)d_in[2];
    const float* qkv_b  = (const float*)d_in[3];
    const float* proj_w = (const float*)d_in[4];
    const float* proj_b = (const float*)d_in[5];
    const float* pw     = (const float*)d_in[6];
    float* out = (float*)d_out;
    char* ws = (char*)d_ws;

    unsigned short* x_bf    = (unsigned short*)(ws);                   // 8 MB (reused as attn_bf)
    unsigned short* w1_bf   = (unsigned short*)(ws + (8u  << 20));     // 6 MB
    unsigned short* wp_bf   = (unsigned short*)(ws + (14u << 20));     // 2 MB
    unsigned short* qb      = (unsigned short*)(ws + (16u << 20));     // 8 MB
    unsigned short* kfrag   = (unsigned short*)(ws + (24u << 20));     // 8 MB
    unsigned short* vfrag   = (unsigned short*)(ws + (32u << 20));     // 8 MB
    unsigned short* attn_bf = x_bf;

    cvt_bf16_kernel<<<4096, 256, 0, stream>>>(x,      x_bf,  1048576);
    cvt_bf16_kernel<<<3072, 256, 0, stream>>>(qkv_w,  w1_bf, 786432);
    cvt_bf16_kernel<<<1024, 256, 0, stream>>>(proj_w, wp_bf, 262144);

    gemm_qkv<<<dim3(16, 12), 512, 0, stream>>>(x_bf, w1_bf, qkv_b, ps, pw, qb, kfrag, vfrag);
    attn_kernel<<<dim3(16, 32), 256, 0, stream>>>(qb, kfrag, vfrag, attn_bf);
    gemm_proj<<<dim3(32, 8), 256, 0, stream>>>(attn_bf, wp_bf, proj_b, out);
}